// Round 7
// baseline (333.351 us; speedup 1.0000x reference)
//
#include <hip/hip_runtime.h>
#include <hip/hip_bf16.h>

#define BATCH 4096

typedef __attribute__((ext_vector_type(8))) short short8;
typedef __attribute__((ext_vector_type(4))) short short4_t;
typedef __attribute__((ext_vector_type(4))) float f32x4;

#define MFMA_BF16 __builtin_amdgcn_mfma_f32_16x16x32_bf16

// light barrier: drains LDS ops then block-barrier (block = the 2-wave pair);
// global loads stay in flight across it
#define LBAR() asm volatile("s_waitcnt lgkmcnt(0)\n\ts_barrier" ::: "memory")

__device__ __forceinline__ float frelu(float v) { return v > 0.f ? v : 0.f; }
__device__ __forceinline__ unsigned short f2bf(float f) {
    return __builtin_bit_cast(unsigned short, __float2bfloat16(f));
}

// ---------------- prep: permute+cvt weights to bf16 K-contiguous layouts; init out ----------------
__global__ __launch_bounds__(256) void prep_kernel(const float* __restrict__ w1, const float* __restrict__ w2,
                                                   const float* __restrict__ w3, const float* __restrict__ w4,
                                                   const float* __restrict__ b5,
                                                   unsigned short* __restrict__ w1p, unsigned short* __restrict__ w2p,
                                                   unsigned short* __restrict__ w3p, unsigned short* __restrict__ w4p,
                                                   float* __restrict__ out) {
    int idx = blockIdx.x * 256 + threadIdx.x;
    if (idx < 6144) {
        w1p[idx] = f2bf(w1[idx]);
    } else if (idx < 24576) {
        int j = idx - 6144;
        int oc = j / 288, k = j % 288;
        int khw = k / 32, ic = k % 32;
        w2p[j] = f2bf(w2[oc * 288 + ic * 9 + khw]);
    } else if (idx < 61440) {
        int j = idx - 24576;
        int oc = j / 576, k = j % 576;
        int khw = k / 64, ic = k % 64;
        w3p[j] = f2bf(w3[oc * 576 + ic * 9 + khw]);
    } else if (idx < 552960) {
        int j = idx - 61440;
        int n = j / 960, k = j % 960;
        int pos = k / 64, oc = k % 64;
        w4p[j] = f2bf(w4[n * 960 + oc * 15 + pos]);
    } else if (idx < 561152) {
        int j = idx - 552960;
        out[j] = b5[j & 1];
    } else if (idx < 561367) {
        out[8192 + (idx - 561152)] = 0.f;
    }
}

// ---------------- fused convs: ONE IMAGE PER 2-WAVE BLOCK, burst-loaded weights ----------------
// Block = 2 waves (p=0,1) sharing one 19,584B slab: ub=[144][68] image bf16; x2l=[165][36]
// overlays ub after conv1; x4l=[35][72] at +5952. conv1 m-tiles split by parity; conv2/conv3
// split by 32-oc halves. All weight loads are single fully-unrolled register bursts (one
// latency exposure per phase). __launch_bounds__(128,4): 128-VGPR budget, 8 blocks/CU.
__global__ __launch_bounds__(128, 4) void fused_convs(const float* __restrict__ x,
                                                      const unsigned short* __restrict__ w1p, const float* __restrict__ b1,
                                                      const unsigned short* __restrict__ w2p, const float* __restrict__ b2,
                                                      const unsigned short* __restrict__ w3p, const float* __restrict__ b3,
                                                      unsigned short* __restrict__ x6, float* __restrict__ redbuf) {
    __shared__ __align__(16) unsigned short ub[9792];     // 19,584 B -> 8 blocks/CU
    const int tid = threadIdx.x;
    const int lane = tid & 63;
    const int col = lane & 15, quad = lane >> 4;
    const int p = tid >> 6;                               // wave = oc-half / tile-parity
    const int img = blockIdx.x;

    unsigned short* x2l = ub;               // [165][36] overlays ub after conv1
    unsigned short* x4l = ub + 5952;        // [35][72]  (byte 11904, 16B aligned)
    float* vrow = redbuf + ((size_t)img * 2 + p) * 216;   // this wave's virtual partial row

    // ---- stage image: single 18-deep float4 burst per lane ----
    {
        const float4* xs = (const float4*)(x + (size_t)img * 9216);
        float4 t[18];
        #pragma unroll
        for (int i = 0; i < 18; ++i) t[i] = xs[i * 128 + p * 64 + lane];
        #pragma unroll
        for (int i = 0; i < 18; ++i) {
            const int idx = i * 128 + p * 64 + lane;
            const int r = idx >> 4, cf = (idx & 15) * 4;
            short4_t s;
            s[0] = (short)f2bf(t[i].x); s[1] = (short)f2bf(t[i].y);
            s[2] = (short)f2bf(t[i].z); s[3] = (short)f2bf(t[i].w);
            *(short4_t*)(ub + r * 68 + cf) = s;
        }
    }
    LBAR();

    // ---- conv1: tiles t = 2*ti+p (6 or 5), N=32, K=192 (6 chunks); weights burst (12) ----
    {
        short8 Bf1[2][6];
        #pragma unroll
        for (int nt = 0; nt < 2; ++nt) {
            const unsigned short* wb = w1p + (size_t)(nt * 16 + col) * 192 + quad * 8;
            #pragma unroll
            for (int c = 0; c < 6; ++c) Bf1[nt][c] = *(const short8*)(wb + c * 32);
        }
        f32x4 c1a[6][2] = {};
        #pragma unroll
        for (int ti = 0; ti < 6; ++ti) {
            const int t = ti * 2 + p;
            if (t >= 11) break;
            const int posA = t * 16 + col;
            const int pm = posA < 165 ? posA : 164;
            const int oh = pm / 15, ow = pm % 15;
            #pragma unroll
            for (int c = 0; c < 6; ++c) {
                const int ic = c >> 1;
                const int kh = (c & 1) * 4 + quad;
                const unsigned short* ap = ub + (ic * 48 + oh * 4 + kh) * 68 + ow * 4;
                short8 af;
                *(short4_t*)&af       = *(const short4_t*)ap;
                *((short4_t*)&af + 1) = *(const short4_t*)(ap + 4);
                c1a[ti][0] = MFMA_BF16(af, Bf1[0][c], c1a[ti][0], 0, 0, 0);
                c1a[ti][1] = MFMA_BF16(af, Bf1[1][c], c1a[ti][1], 0, 0, 0);
            }
        }
        LBAR();   // both waves' image reads done -> x2l may overlay ub

        // ---- conv1 epilogue: bias/relu -> x2l; ave1 -> vrow; zero non-owned rows ----
        const float bias0 = b1[col], bias1 = b1[col + 16];
        #pragma unroll
        for (int ti = 0; ti < 6; ++ti) {
            const int t = ti * 2 + p;
            if (t >= 11) break;
            #pragma unroll
            for (int r = 0; r < 4; ++r) {
                const int pr = t * 16 + quad * 4 + r;
                float v0 = c1a[ti][0][r] + bias0;
                float v1 = c1a[ti][1][r] + bias1;
                float s = v0 + v1;
                s += __shfl_xor(s, 1); s += __shfl_xor(s, 2);
                s += __shfl_xor(s, 4); s += __shfl_xor(s, 8);
                if (pr < 165) {
                    x2l[pr * 36 + col]      = f2bf(frelu(v0));
                    x2l[pr * 36 + col + 16] = f2bf(frelu(v1));
                    if (col == 0) vrow[pr] = s;
                }
            }
        }
        for (int i = lane; i < 165; i += 64)
            if (((i >> 4) & 1) != p) vrow[i] = 0.f;   // rows owned by the other wave
    }
    LBAR();

    // ---- conv2: M=35 (3 m-tiles), this wave's 32-oc half, K=288; weights burst (18) ----
    {
        short8 W2[18];                                    // [c][n] : 72 VGPR, one exposure
        #pragma unroll
        for (int c = 0; c < 9; ++c)
            #pragma unroll
            for (int n = 0; n < 2; ++n)
                W2[c * 2 + n] = *(const short8*)(w2p + (size_t)(p * 32 + n * 16 + col) * 288 + c * 32 + quad * 8);
        int aoff[3];
        #pragma unroll
        for (int mt = 0; mt < 3; ++mt) {
            int pp = mt * 16 + col; pp = pp < 35 ? pp : 34;
            aoff[mt] = ((pp / 7) * 30 + (pp % 7) * 2) * 36 + quad * 8;
        }
        f32x4 a2[3][2] = {};
        #pragma unroll
        for (int c = 0; c < 9; ++c) {
            const int koff = ((c / 3) * 15 + (c % 3)) * 36;
            short8 A[3];
            #pragma unroll
            for (int mt = 0; mt < 3; ++mt) {
                const unsigned short* ap = x2l + aoff[mt] + koff;
                *(short4_t*)&A[mt]       = *(const short4_t*)ap;
                *((short4_t*)&A[mt] + 1) = *(const short4_t*)(ap + 4);
            }
            #pragma unroll
            for (int n = 0; n < 2; ++n)
                #pragma unroll
                for (int mt = 0; mt < 3; ++mt)
                    a2[mt][n] = MFMA_BF16(A[mt], W2[c * 2 + n], a2[mt][n], 0, 0, 0);
        }
        float bv2[2];
        #pragma unroll
        for (int n = 0; n < 2; ++n) bv2[n] = b2[p * 32 + n * 16 + col];
        #pragma unroll
        for (int mt = 0; mt < 3; ++mt) {
            #pragma unroll
            for (int r = 0; r < 4; ++r) {
                const int pr = mt * 16 + quad * 4 + r;
                if (pr < 35) {
                    float s = 0.f;
                    #pragma unroll
                    for (int n = 0; n < 2; ++n) {
                        float v = a2[mt][n][r] + bv2[n];
                        s += v;
                        x4l[pr * 72 + p * 32 + n * 16 + col] = f2bf(frelu(v));
                    }
                    s += __shfl_xor(s, 1); s += __shfl_xor(s, 2);
                    s += __shfl_xor(s, 4); s += __shfl_xor(s, 8);
                    if (col == 0) vrow[165 + pr] = s;   // 32-oc partial; halves summed in reduce
                }
            }
        }
    }
    LBAR();

    // ---- conv3: M=15, this wave's 32-oc half, K=576; two 18-deep weight bursts ----
    {
        int pp = col < 15 ? col : 14;
        const int abase = ((pp / 5) * 7 + (pp % 5)) * 72;
        f32x4 a3[2] = {};
        #pragma unroll
        for (int n = 0; n < 2; ++n) {
            short8 W3[18];                                // 72 VGPR, one exposure per n-slice
            const unsigned short* wb = w3p + (size_t)(p * 32 + n * 16 + col) * 576 + quad * 8;
            #pragma unroll
            for (int k = 0; k < 18; ++k) W3[k] = *(const short8*)(wb + k * 32);
            #pragma unroll
            for (int cc = 0; cc < 9; ++cc) {
                const unsigned short* bp = x4l + abase + ((cc / 3) * 7 + (cc % 3)) * 72 + quad * 8;
                short8 af0 = *(const short8*)bp;          // ic 0..31  (16B aligned)
                short8 af1 = *(const short8*)(bp + 32);   // ic 32..63
                a3[n] = MFMA_BF16(af0, W3[2 * cc],     a3[n], 0, 0, 0);
                a3[n] = MFMA_BF16(af1, W3[2 * cc + 1], a3[n], 0, 0, 0);
            }
        }
        float bv3[2];
        #pragma unroll
        for (int n = 0; n < 2; ++n) bv3[n] = b3[p * 32 + n * 16 + col];
        unsigned short* xout = x6 + (size_t)img * 960;
        #pragma unroll
        for (int r = 0; r < 4; ++r) {
            const int pr = quad * 4 + r;
            if (pr < 15) {
                float s = 0.f;
                #pragma unroll
                for (int n = 0; n < 2; ++n) {
                    float v = a3[n][r] + bv3[n];
                    s += v;
                    xout[pr * 64 + p * 32 + n * 16 + col] = f2bf(frelu(v));
                }
                s += __shfl_xor(s, 1); s += __shfl_xor(s, 2);
                s += __shfl_xor(s, 4); s += __shfl_xor(s, 8);
                if (col == 0) vrow[200 + pr] = s;     // 32-oc partial
            }
        }
    }
}

// ---------------- reduce: out[8192+row] = sum over 8192 virtual rows * scale ----------------
__global__ __launch_bounds__(256) void reduce_aves(const float* __restrict__ redbuf, float* __restrict__ out) {
    const int row = blockIdx.x;
    float s = 0.f;
    for (int i = threadIdx.x; i < 8192; i += 256) s += redbuf[(size_t)i * 216 + row];
    s += __shfl_down(s, 32); s += __shfl_down(s, 16); s += __shfl_down(s, 8);
    s += __shfl_down(s, 4);  s += __shfl_down(s, 2);  s += __shfl_down(s, 1);
    __shared__ float wsum[4];
    if ((threadIdx.x & 63) == 0) wsum[threadIdx.x >> 6] = s;
    __syncthreads();
    if (threadIdx.x == 0)
        out[8192 + row] = (wsum[0] + wsum[1] + wsum[2] + wsum[3]) * (row < 165 ? 0.03125f : 0.015625f);
}

// ---------------- fc4+fc5: out[b,2] += relu(x6@w4p^T + b4) @ w5^T ----------------
__global__ __launch_bounds__(256) void fc45_mfma(const unsigned short* __restrict__ x6,
                                                 const unsigned short* __restrict__ w4p, const float* __restrict__ b4,
                                                 const float* __restrict__ w5, float* __restrict__ out) {
    __shared__ float outl[32][2];
    const int tid = threadIdx.x;
    const int wave = tid >> 6, lane = tid & 63;
    const int col = lane & 15, quad = lane >> 4;
    if (tid < 64) outl[tid >> 1][tid & 1] = 0.f;
    const int m0 = blockIdx.x * 32;
    const int oc = blockIdx.y * 64 + wave * 16 + col;

    const unsigned short* brow  = w4p + (size_t)oc * 960 + quad * 8;
    const unsigned short* arow0 = x6 + (size_t)(m0 + col) * 960 + quad * 8;
    const unsigned short* arow1 = arow0 + 16 * 960;
    f32x4 acc0 = {}, acc1 = {};
    __syncthreads();
    #pragma unroll 6
    for (int c = 0; c < 30; ++c) {
        short8 Bf = *(const short8*)(brow + c * 32);
        short8 a0 = *(const short8*)(arow0 + c * 32);
        short8 a1 = *(const short8*)(arow1 + c * 32);
        acc0 = MFMA_BF16(a0, Bf, acc0, 0, 0, 0);
        acc1 = MFMA_BF16(a1, Bf, acc1, 0, 0, 0);
    }
    const float bb = b4[oc], u0 = w5[oc], u1 = w5[512 + oc];
    #pragma unroll
    for (int mi = 0; mi < 2; ++mi) {
        const f32x4 acc = mi ? acc1 : acc0;
        #pragma unroll
        for (int r = 0; r < 4; ++r) {
            float h = frelu(acc[r] + bb);
            float l0 = h * u0, l1 = h * u1;
            l0 += __shfl_xor(l0, 1); l0 += __shfl_xor(l0, 2); l0 += __shfl_xor(l0, 4); l0 += __shfl_xor(l0, 8);
            l1 += __shfl_xor(l1, 1); l1 += __shfl_xor(l1, 2); l1 += __shfl_xor(l1, 4); l1 += __shfl_xor(l1, 8);
            if (col == 0) {
                atomicAdd(&outl[mi * 16 + quad * 4 + r][0], l0);
                atomicAdd(&outl[mi * 16 + quad * 4 + r][1], l1);
            }
        }
    }
    __syncthreads();
    if (tid < 64) atomicAdd(&out[(m0 + (tid >> 1)) * 2 + (tid & 1)], outl[tid >> 1][tid & 1]);
}

extern "C" void kernel_launch(void* const* d_in, const int* in_sizes, int n_in,
                              void* d_out, int out_size, void* d_ws, size_t ws_size,
                              hipStream_t stream) {
    const float* x  = (const float*)d_in[0];
    const float* w1 = (const float*)d_in[1];
    const float* b1 = (const float*)d_in[2];
    const float* w2 = (const float*)d_in[3];
    const float* b2 = (const float*)d_in[4];
    const float* w3 = (const float*)d_in[5];
    const float* b3 = (const float*)d_in[6];
    const float* w4 = (const float*)d_in[7];
    const float* b4 = (const float*)d_in[8];
    const float* w5 = (const float*)d_in[9];
    const float* b5 = (const float*)d_in[10];
    float* out = (float*)d_out;

    unsigned short* ws = (unsigned short*)d_ws;
    unsigned short* x6  = ws;                      // 3,932,160 ushort
    unsigned short* w1p = ws + 3932160;            //      6,144
    unsigned short* w2p = ws + 3938304;            //     18,432
    unsigned short* w3p = ws + 3956736;            //     36,864
    unsigned short* w4p = ws + 3993600;            //    491,520
    float* redbuf = (float*)((char*)d_ws + 8970240); // 8192*216 floats = 7,077,888 B

    prep_kernel<<<2193, 256, 0, stream>>>(w1, w2, w3, w4, b5, w1p, w2p, w3p, w4p, out);
    fused_convs<<<BATCH, 128, 0, stream>>>(x, w1p, b1, w2p, b2, w3p, b3, x6, redbuf);
    reduce_aves<<<215, 256, 0, stream>>>(redbuf, out);
    fc45_mfma<<<dim3(128, 8), 256, 0, stream>>>(x6, w4p, b4, w5, out);
}